// Round 9
// baseline (382.561 us; speedup 1.0000x reference)
//
#include <hip/hip_runtime.h>

using v8s = __attribute__((ext_vector_type(8))) short;          // 8 bf16 MFMA frag
using v4f = __attribute__((ext_vector_type(4))) float;          // MFMA acc
using v4u = __attribute__((ext_vector_type(4))) unsigned short; // 8B packed
using v8u = __attribute__((ext_vector_type(8))) unsigned short; // 16B copy

// fp32 -> bf16 RNE
__device__ __forceinline__ unsigned short f2b(float x) {
  unsigned int u = __builtin_bit_cast(unsigned int, x);
  return (unsigned short)((u + 0x7FFFu + ((u >> 16) & 1u)) >> 16);
}
// bf16 -> fp32
__device__ __forceinline__ float b2f(unsigned short u) {
  unsigned int v = ((unsigned int)u) << 16;
  return __builtin_bit_cast(float, v);
}

// async global -> LDS, 16 bytes per lane (global_load_lds_dwordx4)
__device__ __forceinline__ void gl_lds16(const unsigned short* g, unsigned short* l) {
  __builtin_amdgcn_global_load_lds(
      (const __attribute__((address_space(1))) unsigned int*)g,
      (__attribute__((address_space(3))) unsigned int*)l, 16, 0, 0);
}

// ---------------------------------------------------------------------------
// f32 -> bf16 bulk convert, 8 elems/thread
// ---------------------------------------------------------------------------
__global__ void cvt_kernel(const float* __restrict__ src,
                           unsigned short* __restrict__ dst, int n8) {
  int i = blockIdx.x * 256 + threadIdx.x;
  if (i >= n8) return;
  const float* p = src + (size_t)i * 8;
  float4 a = *(const float4*)p;
  float4 b = *(const float4*)(p + 4);
  v8u o = {f2b(a.x), f2b(a.y), f2b(a.z), f2b(a.w),
           f2b(b.x), f2b(b.y), f2b(b.z), f2b(b.w)};
  *(v8u*)(dst + (size_t)i * 8) = o;
}

// ---------------------------------------------------------------------------
// Pure-bf16 GEMM, m97 recipe: 128x128 tile, BK=32, async width-16 staging.
// MODE 1 (QKV): cols<1536 -> C bf16 (ldc=1536); cols>=1536 -> VT transposed.
// MODE 0: plain store (f32 if OF).
// ---------------------------------------------------------------------------
template <int MODE, bool OF>
__global__ __launch_bounds__(256, 2)
void gemm_async_kernel(const unsigned short* __restrict__ A,
                       const unsigned short* __restrict__ Bw,
                       void* __restrict__ Cv, unsigned short* __restrict__ VT,
                       int K, int ldc) {
  __shared__ unsigned short As[4096];
  __shared__ unsigned short Bs[4096];

  const int t    = threadIdx.x;
  const int ln   = t & 63;
  const int wv   = t >> 6;
  const int quad = ln >> 4;
  const int L    = ln & 15;
  const int wm   = (wv >> 1) * 64;
  const int wn   = (wv & 1) * 64;
  const long m0  = (long)blockIdx.y * 128;
  const long n0  = (long)blockIdx.x * 128;

  v4f acc[4][4];
#pragma unroll
  for (int i = 0; i < 4; i++)
#pragma unroll
    for (int j = 0; j < 4; j++) acc[i][j] = (v4f){0.f, 0.f, 0.f, 0.f};

  const int ar = t >> 2;
  const int ac = (t & 3) * 8;
  const unsigned short* Ag = A + (m0 + ar) * (long)K + ac;
  const unsigned short* Bg = Bw + (n0 + ar) * (long)K + ac;
  unsigned short* la = &As[t * 8];
  unsigned short* lb = &Bs[t * 8];
  const long rowskip = 64L * K;

  for (int k0 = 0; k0 < K; k0 += 32) {
    gl_lds16(Ag + k0, la);
    gl_lds16(Ag + rowskip + k0, la + 2048);
    gl_lds16(Bg + k0, lb);
    gl_lds16(Bg + rowskip + k0, lb + 2048);
    __syncthreads();

    v8s af[4], bfr[4];
#pragma unroll
    for (int i = 0; i < 4; i++)
      af[i] = *(const v8s*)(&As[(wm + i * 16 + L) * 32 + quad * 8]);
#pragma unroll
    for (int j = 0; j < 4; j++)
      bfr[j] = *(const v8s*)(&Bs[(wn + j * 16 + L) * 32 + quad * 8]);
#pragma unroll
    for (int i = 0; i < 4; i++)
#pragma unroll
      for (int j = 0; j < 4; j++)
        acc[i][j] = __builtin_amdgcn_mfma_f32_16x16x32_bf16(af[i], bfr[j], acc[i][j], 0, 0, 0);
    __syncthreads();
  }

  if (MODE == 0 || n0 < 1536) {
#pragma unroll
    for (int i = 0; i < 4; i++)
#pragma unroll
      for (int j = 0; j < 4; j++)
#pragma unroll
        for (int r = 0; r < 4; r++) {
          long row = m0 + wm + i * 16 + quad * 4 + r;
          long col = n0 + wn + j * 16 + L;
          if (OF) ((float*)Cv)[row * ldc + col] = acc[i][j][r];
          else    ((unsigned short*)Cv)[row * ldc + col] = f2b(acc[i][j][r]);
        }
  } else {
#pragma unroll
    for (int i = 0; i < 4; i++)
#pragma unroll
      for (int j = 0; j < 4; j++) {
        int colp   = (int)(n0 + wn + j * 16 + L) - 1536;
        int h      = colp >> 8;
        int d      = colp & 255;
        long token = m0 + wm + i * 16 + quad * 4;
        int b  = (int)(token >> 11);
        int tk = (int)(token & 2047);
        v4u val = {f2b(acc[i][j][0]), f2b(acc[i][j][1]), f2b(acc[i][j][2]), f2b(acc[i][j][3])};
        *(v4u*)(&VT[((long)(b * 3 + h) * 256 + d) * 2048 + tk]) = val;
      }
  }
}

// ---------------------------------------------------------------------------
// Split-K flash attention partials, chunk = CH key-tiles (CH*32 keys).
// Block = (bh, qtile t of 64 rows, chunk c); 4 waves x 16 q-rows.
// K tiles staged in LDS (4-way reuse); V frags DIRECT from transposed VT
// (contiguous 16B loads). Writes normalized partial Ohat=O/l (bf16) + m,l.
// chunks per qtile t = ceil((2t+2)/CH); blockIdx.x packs (t,c).
// ---------------------------------------------------------------------------
template <int CH>
__global__ __launch_bounds__(256, 2)
void attn_part_kernel(const unsigned short* __restrict__ QK,
                      const unsigned short* __restrict__ VT,
                      unsigned short* __restrict__ Part,
                      float* __restrict__ ML) {
  __shared__ unsigned short Ks[32 * 264];    // [key 32][d 256 + pad 8]
  __shared__ unsigned short Ps[4 * 16 * 40]; // per-wave [q 16][key 32 + pad 8]

  const int tt   = threadIdx.x;
  const int wv   = tt >> 6;
  const int ln   = tt & 63;
  const int quad = ln >> 4;
  const int L    = ln & 15;

  // decode packed (t, c)
  int rem = (int)blockIdx.x, t = 0;
  for (;;) {
    int n = (2 * t + 2 + CH - 1) / CH;
    if (rem < n) break;
    rem -= n; t++;
  }
  const int c = rem;

  const int bh   = (int)blockIdx.y;
  const int b    = bh / 3, h = bh % 3;
  const int qrow = t * 64 + wv * 16;
  const long tokbase = (long)b * 2048;
  const long slot = (long)bh * gridDim.x + blockIdx.x;

  v8s qf[8];
  {
    const unsigned short* Qb = QK + (tokbase + qrow + L) * 1536 + h * 256 + quad * 8;
#pragma unroll
    for (int kc = 0; kc < 8; kc++) qf[kc] = *(const v8s*)(Qb + kc * 32);
  }

  v4f o[16];
#pragma unroll
  for (int dt = 0; dt < 16; dt++) o[dt] = (v4f){0.f, 0.f, 0.f, 0.f};
  float mrow[4] = {-1e9f, -1e9f, -1e9f, -1e9f};
  float lrow[4] = {0.f, 0.f, 0.f, 0.f};

  const unsigned short* Kg = QK + tokbase * 1536 + 768 + h * 256;
  // V base: lane reads VT row (bh*256 + dt*16 + L), cols kglob + quad*8..+7
  const unsigned short* Vg = VT + ((long)bh * 256 + L) * 2048 + quad * 8;

  const int nkt = min(CH, 2 * t + 2 - CH * c);
  for (int kt = 0; kt < nkt; kt++) {
    const int kglob = (c * CH + kt) * 32;
    __syncthreads();  // prior Ks reads done
    // stage K tile [32 keys][256 d] : 4 passes x 256 thr x 16B
#pragma unroll
    for (int p = 0; p < 4; p++) {
      int idx = p * 256 + tt;
      int kn = idx >> 5, kc = idx & 31;
      *(v8u*)(&Ks[kn * 264 + kc * 8]) =
          *(const v8u*)(Kg + (long)(kglob + kn) * 1536 + kc * 8);
    }
    __syncthreads();

    if (kglob <= qrow) {  // wave-uniform causal guard
      v4f s0 = (v4f){0.f, 0.f, 0.f, 0.f}, s1 = s0;
#pragma unroll
      for (int kc = 0; kc < 8; kc++) {
        v8s kf0 = *(const v8s*)(&Ks[L * 264 + kc * 32 + quad * 8]);
        v8s kf1 = *(const v8s*)(&Ks[(16 + L) * 264 + kc * 32 + quad * 8]);
        s0 = __builtin_amdgcn_mfma_f32_16x16x32_bf16(qf[kc], kf0, s0, 0, 0, 0);
        s1 = __builtin_amdgcn_mfma_f32_16x16x32_bf16(qf[kc], kf1, s1, 0, 0, 0);
      }
      float al[4], p0[4], p1[4];
#pragma unroll
      for (int r = 0; r < 4; r++) {
        int row = qrow + quad * 4 + r;
        int c0  = kglob + L;
        float v0 = (c0 <= row) ? s0[r] * 0.0625f : -1e9f;
        float v1 = (c0 + 16 <= row) ? s1[r] * 0.0625f : -1e9f;
        float mx = fmaxf(v0, v1);
        mx = fmaxf(mx, __shfl_xor(mx, 1));
        mx = fmaxf(mx, __shfl_xor(mx, 2));
        mx = fmaxf(mx, __shfl_xor(mx, 4));
        mx = fmaxf(mx, __shfl_xor(mx, 8));
        float mn = fmaxf(mrow[r], mx);
        float a  = __expf(mrow[r] - mn);
        float e0 = __expf(v0 - mn);
        float e1 = __expf(v1 - mn);
        float sm = e0 + e1;
        sm += __shfl_xor(sm, 1);
        sm += __shfl_xor(sm, 2);
        sm += __shfl_xor(sm, 4);
        sm += __shfl_xor(sm, 8);
        mrow[r] = mn;
        lrow[r] = lrow[r] * a + sm;
        al[r] = a; p0[r] = e0; p1[r] = e1;
      }
#pragma unroll
      for (int dt = 0; dt < 16; dt++)
#pragma unroll
        for (int r = 0; r < 4; r++) o[dt][r] *= al[r];
      // P: C-layout -> per-wave LDS -> A-layout
      unsigned short* Pw = &Ps[wv * 640 + (quad * 4) * 40 + L];
#pragma unroll
      for (int r = 0; r < 4; r++) {
        Pw[r * 40]      = f2b(p0[r]);
        Pw[r * 40 + 16] = f2b(p1[r]);
      }
      __threadfence_block();
      v8s pf = *(const v8s*)(&Ps[wv * 640 + L * 40 + quad * 8]);
      // O += P V : B-frags direct from global VT (independent loads, indep MFMAs)
      const unsigned short* pV = Vg + kglob;
#pragma unroll
      for (int dt = 0; dt < 16; dt++) {
        v8s vf = *(const v8s*)(pV + (long)dt * 16 * 2048);
        o[dt] = __builtin_amdgcn_mfma_f32_16x16x32_bf16(pf, vf, o[dt], 0, 0, 0);
      }
    }
  }

  // epilogue: normalized partial + (m, l)
  float inv[4];
#pragma unroll
  for (int r = 0; r < 4; r++) inv[r] = 1.0f / lrow[r];  // l>0: diagonal always present
  unsigned short* Pb = Part + slot * 16384;  // [64 rows][256 cols]
#pragma unroll
  for (int dt = 0; dt < 16; dt++)
#pragma unroll
    for (int r = 0; r < 4; r++) {
      int rowl = wv * 16 + quad * 4 + r;
      Pb[rowl * 256 + dt * 16 + L] = f2b(o[dt][r] * inv[r]);
    }
  if (L == 0) {
    float* mlb = ML + slot * 128;
#pragma unroll
    for (int r = 0; r < 4; r++) {
      int rowl = wv * 16 + quad * 4 + r;
      mlb[rowl * 2]     = mrow[r];
      mlb[rowl * 2 + 1] = lrow[r];
    }
  }
}

// ---------------------------------------------------------------------------
// Combine <=8 chunk partials per (bh, qtile). Block=(t, bh), 256 thr.
// ---------------------------------------------------------------------------
template <int CH>
__global__ __launch_bounds__(256, 2)
void attn_reduce_kernel(const unsigned short* __restrict__ Part,
                        const float* __restrict__ ML,
                        unsigned short* __restrict__ Out, int spb) {
  const int t  = (int)blockIdx.x;
  const int bh = (int)blockIdx.y;
  const int b  = bh / 3, h = bh % 3;
  int off = 0;
  for (int u = 0; u < t; u++) off += (2 * u + 2 + CH - 1) / CH;
  const int nch = (2 * t + 2 + CH - 1) / CH;
  const long slot0 = (long)bh * spb + off;

  const int tid = threadIdx.x;
  const int row = tid >> 2;
  const int cs  = (tid & 3) * 64;

  float mc[8], lc[8];
  float M = -1e30f;
  for (int c = 0; c < nch; c++) {
    const float* mlb = ML + (slot0 + c) * 128 + row * 2;
    mc[c] = mlb[0];
    lc[c] = mlb[1];
    M = fmaxf(M, mc[c]);
  }
  float wn[8], S = 0.f;
  for (int c = 0; c < nch; c++) { wn[c] = __expf(mc[c] - M) * lc[c]; S += wn[c]; }
  const float invS = 1.0f / S;
  for (int c = 0; c < nch; c++) wn[c] *= invS;

  unsigned short* Or = Out + ((long)b * 2048 + t * 64 + row) * 768 + h * 256 + cs;
#pragma unroll
  for (int j = 0; j < 8; j++) {
    float acc[8] = {0.f, 0.f, 0.f, 0.f, 0.f, 0.f, 0.f, 0.f};
    for (int c = 0; c < nch; c++) {
      v8u p = *(const v8u*)(Part + (slot0 + c) * 16384 + row * 256 + cs + j * 8);
#pragma unroll
      for (int e = 0; e < 8; e++) acc[e] += wn[c] * b2f(p[e]);
    }
    v8u ov = {f2b(acc[0]), f2b(acc[1]), f2b(acc[2]), f2b(acc[3]),
              f2b(acc[4]), f2b(acc[5]), f2b(acc[6]), f2b(acc[7])};
    *(v8u*)(Or + j * 8) = ov;
  }
}

// ---------------------------------------------------------------------------
extern "C" void kernel_launch(void* const* d_in, const int* in_sizes, int n_in,
                              void* d_out, int out_size, void* d_ws, size_t ws_size,
                              hipStream_t stream) {
  const float* X     = (const float*)d_in[0];  // [4,2048,768] f32
  const float* Wqkv  = (const float*)d_in[1];  // [2304,768]   f32
  const float* Wproj = (const float*)d_in[2];  // [768,768]    f32
  float* out = (float*)d_out;                  // [4,2048,768] f32

  const size_t SZ_QK = (size_t)8192 * 1536 * 2;  // 25.2 MB
  const size_t SZ_VT = (size_t)3072 * 2048 * 2;  // 12.6 MB
  const size_t SZ_AO = (size_t)8192 * 768 * 2;   // 12.6 MB
  const size_t SZ_WQ = (size_t)2304 * 768 * 2;   //  3.5 MB
  const size_t SZ_WP = (size_t)768 * 768 * 2;    //  1.2 MB
  // slots/bh for chunk CH: sum over t=0..31 of ceil((2t+2)/CH)
  // CH=8 -> 144, CH=12 -> 106, CH=16 -> 80
  auto total = [&](int spb) {
    return SZ_QK + SZ_VT + (size_t)12 * spb * (32768 + 512) + SZ_AO + SZ_WQ + SZ_WP;
  };
  int CH, spb;
  if (ws_size >= total(144))      { CH = 8;  spb = 144; }
  else if (ws_size >= total(106)) { CH = 12; spb = 106; }
  else                            { CH = 16; spb = 80; }

  char* ws = (char*)d_ws;
  unsigned short* QKb = (unsigned short*)ws;
  unsigned short* VTb = (unsigned short*)(ws + SZ_QK);
  unsigned short* Prt = (unsigned short*)(ws + SZ_QK + SZ_VT);
  unsigned short* Xb  = Prt;  // alias: Xb dead before Prt written
  float*          MLb = (float*)(ws + SZ_QK + SZ_VT + (size_t)12 * spb * 32768);
  char* p2 = ws + SZ_QK + SZ_VT + (size_t)12 * spb * (32768 + 512);
  unsigned short* AOb = (unsigned short*)p2;
  unsigned short* Wqb = (unsigned short*)(p2 + SZ_AO);
  unsigned short* Wpb = (unsigned short*)(p2 + SZ_AO + SZ_WQ);

  dim3 blk(256, 1, 1);
  // 0) one-time f32 -> bf16 conversions
  cvt_kernel<<<dim3(3072, 1, 1), blk, 0, stream>>>(X, Xb, 786432);
  cvt_kernel<<<dim3(864, 1, 1), blk, 0, stream>>>(Wqkv, Wqb, 221184);
  cvt_kernel<<<dim3(288, 1, 1), blk, 0, stream>>>(Wproj, Wpb, 73728);
  // 1) QKV projection (V stored transposed)
  gemm_async_kernel<1, false><<<dim3(18, 64, 1), blk, 0, stream>>>(
      Xb, Wqb, QKb, VTb, 768, 1536);
  // 2a) split-K flash attention partials
  if (CH == 8)
    attn_part_kernel<8><<<dim3(spb, 12, 1), blk, 0, stream>>>(QKb, VTb, Prt, MLb);
  else if (CH == 12)
    attn_part_kernel<12><<<dim3(spb, 12, 1), blk, 0, stream>>>(QKb, VTb, Prt, MLb);
  else
    attn_part_kernel<16><<<dim3(spb, 12, 1), blk, 0, stream>>>(QKb, VTb, Prt, MLb);
  // 2b) combine partials
  if (CH == 8)
    attn_reduce_kernel<8><<<dim3(32, 12, 1), blk, 0, stream>>>(Prt, MLb, AOb, spb);
  else if (CH == 12)
    attn_reduce_kernel<12><<<dim3(32, 12, 1), blk, 0, stream>>>(Prt, MLb, AOb, spb);
  else
    attn_reduce_kernel<16><<<dim3(32, 12, 1), blk, 0, stream>>>(Prt, MLb, AOb, spb);
  // 3) output projection, f32 store
  gemm_async_kernel<0, true><<<dim3(6, 64, 1), blk, 0, stream>>>(
      AOb, Wpb, out, (unsigned short*)nullptr, 768, 768);
}

// Round 10
// 377.970 us; speedup vs baseline: 1.0121x; 1.0121x over previous
//
#include <hip/hip_runtime.h>

using v8h = __attribute__((ext_vector_type(8))) _Float16;       // 8 f16 MFMA frag
using v4f = __attribute__((ext_vector_type(4))) float;          // MFMA acc
using v4u = __attribute__((ext_vector_type(4))) unsigned short; // 8B packed
using v8u = __attribute__((ext_vector_type(8))) unsigned short; // 16B copy

// fp32 <-> fp16
__device__ __forceinline__ unsigned short f2h(float x) {
  _Float16 h = (_Float16)x;
  return __builtin_bit_cast(unsigned short, h);
}
__device__ __forceinline__ float h2f(unsigned short u) {
  return (float)__builtin_bit_cast(_Float16, u);
}

// async global -> LDS, 16 bytes per lane (global_load_lds_dwordx4)
__device__ __forceinline__ void gl_lds16(const unsigned short* g, unsigned short* l) {
  __builtin_amdgcn_global_load_lds(
      (const __attribute__((address_space(1))) unsigned int*)g,
      (__attribute__((address_space(3))) unsigned int*)l, 16, 0, 0);
}

// ---------------------------------------------------------------------------
// f32 -> f16 bulk convert, 8 elems/thread
// ---------------------------------------------------------------------------
__global__ void cvt_kernel(const float* __restrict__ src,
                           unsigned short* __restrict__ dst, int n8) {
  int i = blockIdx.x * 256 + threadIdx.x;
  if (i >= n8) return;
  const float* p = src + (size_t)i * 8;
  float4 a = *(const float4*)p;
  float4 b = *(const float4*)(p + 4);
  v8u o = {f2h(a.x), f2h(a.y), f2h(a.z), f2h(a.w),
           f2h(b.x), f2h(b.y), f2h(b.z), f2h(b.w)};
  *(v8u*)(dst + (size_t)i * 8) = o;
}

// ---------------------------------------------------------------------------
// f16 GEMM, m97 recipe: C[m,n] = sum_k A[m,k]*Bw[n,k], 128x128 tile, BK=32.
// MODE 1 (QKV): cols<1536 -> C f16 (ldc=1536); cols>=1536 -> VT transposed f16.
// MODE 0: plain store (f32 if OF else f16).
// ---------------------------------------------------------------------------
template <int MODE, bool OF>
__global__ __launch_bounds__(256, 2)
void gemm_async_kernel(const unsigned short* __restrict__ A,
                       const unsigned short* __restrict__ Bw,
                       void* __restrict__ Cv, unsigned short* __restrict__ VT,
                       int K, int ldc) {
  __shared__ unsigned short As[4096];
  __shared__ unsigned short Bs[4096];

  const int t    = threadIdx.x;
  const int ln   = t & 63;
  const int wv   = t >> 6;
  const int quad = ln >> 4;
  const int L    = ln & 15;
  const int wm   = (wv >> 1) * 64;
  const int wn   = (wv & 1) * 64;
  const long m0  = (long)blockIdx.y * 128;
  const long n0  = (long)blockIdx.x * 128;

  v4f acc[4][4];
#pragma unroll
  for (int i = 0; i < 4; i++)
#pragma unroll
    for (int j = 0; j < 4; j++) acc[i][j] = (v4f){0.f, 0.f, 0.f, 0.f};

  const int ar = t >> 2;
  const int ac = (t & 3) * 8;
  const unsigned short* Ag = A + (m0 + ar) * (long)K + ac;
  const unsigned short* Bg = Bw + (n0 + ar) * (long)K + ac;
  unsigned short* la = &As[t * 8];
  unsigned short* lb = &Bs[t * 8];
  const long rowskip = 64L * K;

  for (int k0 = 0; k0 < K; k0 += 32) {
    gl_lds16(Ag + k0, la);
    gl_lds16(Ag + rowskip + k0, la + 2048);
    gl_lds16(Bg + k0, lb);
    gl_lds16(Bg + rowskip + k0, lb + 2048);
    __syncthreads();

    v8h af[4], bfr[4];
#pragma unroll
    for (int i = 0; i < 4; i++)
      af[i] = *(const v8h*)(&As[(wm + i * 16 + L) * 32 + quad * 8]);
#pragma unroll
    for (int j = 0; j < 4; j++)
      bfr[j] = *(const v8h*)(&Bs[(wn + j * 16 + L) * 32 + quad * 8]);
#pragma unroll
    for (int i = 0; i < 4; i++)
#pragma unroll
      for (int j = 0; j < 4; j++)
        acc[i][j] = __builtin_amdgcn_mfma_f32_16x16x32_f16(af[i], bfr[j], acc[i][j], 0, 0, 0);
    __syncthreads();
  }

  if (MODE == 0 || n0 < 1536) {
#pragma unroll
    for (int i = 0; i < 4; i++)
#pragma unroll
      for (int j = 0; j < 4; j++)
#pragma unroll
        for (int r = 0; r < 4; r++) {
          long row = m0 + wm + i * 16 + quad * 4 + r;
          long col = n0 + wn + j * 16 + L;
          if (OF) ((float*)Cv)[row * ldc + col] = acc[i][j][r];
          else    ((unsigned short*)Cv)[row * ldc + col] = f2h(acc[i][j][r]);
        }
  } else {
#pragma unroll
    for (int i = 0; i < 4; i++)
#pragma unroll
      for (int j = 0; j < 4; j++) {
        int colp   = (int)(n0 + wn + j * 16 + L) - 1536;
        int h      = colp >> 8;
        int d      = colp & 255;
        long token = m0 + wm + i * 16 + quad * 4;
        int b  = (int)(token >> 11);
        int tk = (int)(token & 2047);
        v4u val = {f2h(acc[i][j][0]), f2h(acc[i][j][1]), f2h(acc[i][j][2]), f2h(acc[i][j][3])};
        *(v4u*)(&VT[((long)(b * 3 + h) * 256 + d) * 2048 + tk]) = val;
      }
  }
}

// ---------------------------------------------------------------------------
// Score GEMM: S_tile(i,j)[128][128] = Q_block_i . K_block_j^T (raw, unscaled).
// Packed lower-tri storage: slot = bh*136 + i(i+1)/2 + j. K=256, 8 iters.
// Grid (136, 12), uniform work.
// ---------------------------------------------------------------------------
__global__ __launch_bounds__(256, 2)
void gemm_sc_kernel(const unsigned short* __restrict__ QK,
                    unsigned short* __restrict__ Sc) {
  __shared__ unsigned short As[4096];
  __shared__ unsigned short Bs[4096];

  const int t    = threadIdx.x;
  const int ln   = t & 63;
  const int wv   = t >> 6;
  const int quad = ln >> 4;
  const int L    = ln & 15;
  const int wm   = (wv >> 1) * 64;
  const int wn   = (wv & 1) * 64;

  // decode packed (i, j): row i has i+1 entries
  int x = (int)blockIdx.x, i = 0;
  while (x >= i + 1) { x -= i + 1; i++; }
  const int j  = x;
  const int bh = (int)blockIdx.y;
  const int b  = bh / 3, h = bh % 3;
  const long tokA = (long)b * 2048 + i * 128;
  const long tokB = (long)b * 2048 + j * 128;

  v4f acc[4][4];
#pragma unroll
  for (int ii = 0; ii < 4; ii++)
#pragma unroll
    for (int jj = 0; jj < 4; jj++) acc[ii][jj] = (v4f){0.f, 0.f, 0.f, 0.f};

  const int ar = t >> 2;
  const int ac = (t & 3) * 8;
  const unsigned short* Ag = QK + (tokA + ar) * 1536 + h * 256 + ac;
  const unsigned short* Bg = QK + (tokB + ar) * 1536 + 768 + h * 256 + ac;
  unsigned short* la = &As[t * 8];
  unsigned short* lb = &Bs[t * 8];
  const long rowskip = 64L * 1536;

  for (int k0 = 0; k0 < 256; k0 += 32) {
    gl_lds16(Ag + k0, la);
    gl_lds16(Ag + rowskip + k0, la + 2048);
    gl_lds16(Bg + k0, lb);
    gl_lds16(Bg + rowskip + k0, lb + 2048);
    __syncthreads();

    v8h af[4], bfr[4];
#pragma unroll
    for (int ii = 0; ii < 4; ii++)
      af[ii] = *(const v8h*)(&As[(wm + ii * 16 + L) * 32 + quad * 8]);
#pragma unroll
    for (int jj = 0; jj < 4; jj++)
      bfr[jj] = *(const v8h*)(&Bs[(wn + jj * 16 + L) * 32 + quad * 8]);
#pragma unroll
    for (int ii = 0; ii < 4; ii++)
#pragma unroll
      for (int jj = 0; jj < 4; jj++)
        acc[ii][jj] = __builtin_amdgcn_mfma_f32_16x16x32_f16(af[ii], bfr[jj], acc[ii][jj], 0, 0, 0);
    __syncthreads();
  }

  unsigned short* Sb = Sc + ((long)bh * 136 + blockIdx.x) * 16384;
#pragma unroll
  for (int ii = 0; ii < 4; ii++)
#pragma unroll
    for (int jj = 0; jj < 4; jj++)
#pragma unroll
      for (int r = 0; r < 4; r++) {
        int row = wm + ii * 16 + quad * 4 + r;
        int col = wn + jj * 16 + L;
        Sb[row * 128 + col] = f2h(acc[ii][jj][r]);
      }
}

// ---------------------------------------------------------------------------
// Softmax over packed causal rows, in place. Block = (i, bh): 128 rows of
// q-block i, row length (i+1)*128. 2 threads/row (halves), 3 passes.
// Masked cols written as exact 0 (participate in PV as zeros).
// ---------------------------------------------------------------------------
__global__ __launch_bounds__(256, 2)
void softmax_kernel(unsigned short* __restrict__ Sc) {
  const int i   = 15 - (int)blockIdx.x;  // heavy first
  const int bh  = (int)blockIdx.y;
  const int tid = threadIdx.x;
  const int row = tid >> 1;
  const int half = tid & 1;

  const long base = ((long)bh * 136 + (long)i * (i + 1) / 2) * 16384 + row * 128;
  const int L = (i + 1) * 128;
  const int r = i * 128 + row;
  const int cbeg = half * (L >> 1), cend = cbeg + (L >> 1);

  float mx = -1e30f;
  for (int c = cbeg; c < cend; c += 8) {
    v8u v = *(const v8u*)(Sc + base + (long)(c >> 7) * 16384 + (c & 127));
#pragma unroll
    for (int e = 0; e < 8; e++)
      if (c + e <= r) mx = fmaxf(mx, h2f(v[e]));
  }
  mx = fmaxf(mx, __shfl_xor(mx, 1));
  mx *= 0.0625f;

  float sum = 0.f;
  for (int c = cbeg; c < cend; c += 8) {
    v8u v = *(const v8u*)(Sc + base + (long)(c >> 7) * 16384 + (c & 127));
#pragma unroll
    for (int e = 0; e < 8; e++)
      if (c + e <= r) sum += __expf(h2f(v[e]) * 0.0625f - mx);
  }
  sum += __shfl_xor(sum, 1);
  const float inv = 1.0f / sum;

  for (int c = cbeg; c < cend; c += 8) {
    unsigned short* p = Sc + base + (long)(c >> 7) * 16384 + (c & 127);
    v8u v = *(const v8u*)p;
    v8u o;
#pragma unroll
    for (int e = 0; e < 8; e++)
      o[e] = (c + e <= r) ? f2h(__expf(h2f(v[e]) * 0.0625f - mx) * inv) : (unsigned short)0;
    *(v8u*)p = o;
  }
}

// ---------------------------------------------------------------------------
// PV GEMM: O_block(i, nh)[128 tok][128 d] = sum_j P_tile(i,j) . V_block_j.
// A = packed P tiles (f16); B staged from transposed VT (Bs[n=d][k=key]).
// Grid x: 32 = (16 i, heavy first) x (2 nh). K-loop: j=0..i, k0=0..96.
// ---------------------------------------------------------------------------
__global__ __launch_bounds__(256, 2)
void gemm_pv_kernel(const unsigned short* __restrict__ Sc,
                    const unsigned short* __restrict__ VT,
                    unsigned short* __restrict__ AO) {
  __shared__ unsigned short As[4096];
  __shared__ unsigned short Bs[4096];

  const int t    = threadIdx.x;
  const int ln   = t & 63;
  const int wv   = t >> 6;
  const int quad = ln >> 4;
  const int L    = ln & 15;
  const int wm   = (wv >> 1) * 64;
  const int wn   = (wv & 1) * 64;

  const int i  = 15 - (int)(blockIdx.x >> 1);  // heavy first
  const int nh = (int)blockIdx.x & 1;
  const int bh = (int)blockIdx.y;
  const int b  = bh / 3, h = bh % 3;

  v4f acc[4][4];
#pragma unroll
  for (int ii = 0; ii < 4; ii++)
#pragma unroll
    for (int jj = 0; jj < 4; jj++) acc[ii][jj] = (v4f){0.f, 0.f, 0.f, 0.f};

  const int ar = t >> 2;
  const int ac = (t & 3) * 8;
  const unsigned short* Abase =
      Sc + ((long)bh * 136 + (long)i * (i + 1) / 2) * 16384 + ar * 128 + ac;
  const unsigned short* Bg =
      VT + ((long)bh * 256 + nh * 128 + ar) * 2048 + ac;
  unsigned short* la = &As[t * 8];
  unsigned short* lb = &Bs[t * 8];

  for (int j = 0; j <= i; j++) {
    const unsigned short* Aj = Abase + (long)j * 16384;
    const unsigned short* Bj = Bg + j * 128;
#pragma unroll
    for (int k0 = 0; k0 < 128; k0 += 32) {
      gl_lds16(Aj + k0, la);
      gl_lds16(Aj + 64 * 128 + k0, la + 2048);
      gl_lds16(Bj + k0, lb);
      gl_lds16(Bj + 64 * 2048 + k0, lb + 2048);
      __syncthreads();

      v8h af[4], bfr[4];
#pragma unroll
      for (int ii = 0; ii < 4; ii++)
        af[ii] = *(const v8h*)(&As[(wm + ii * 16 + L) * 32 + quad * 8]);
#pragma unroll
      for (int jj = 0; jj < 4; jj++)
        bfr[jj] = *(const v8h*)(&Bs[(wn + jj * 16 + L) * 32 + quad * 8]);
#pragma unroll
      for (int ii = 0; ii < 4; ii++)
#pragma unroll
        for (int jj = 0; jj < 4; jj++)
          acc[ii][jj] = __builtin_amdgcn_mfma_f32_16x16x32_f16(af[ii], bfr[jj], acc[ii][jj], 0, 0, 0);
      __syncthreads();
    }
  }

#pragma unroll
  for (int ii = 0; ii < 4; ii++)
#pragma unroll
    for (int jj = 0; jj < 4; jj++)
#pragma unroll
      for (int r = 0; r < 4; r++) {
        long row = (long)b * 2048 + i * 128 + wm + ii * 16 + quad * 4 + r;
        int  col = h * 256 + nh * 128 + wn + jj * 16 + L;
        AO[row * 768 + col] = f2h(acc[ii][jj][r]);
      }
}

// ---------------------------------------------------------------------------
extern "C" void kernel_launch(void* const* d_in, const int* in_sizes, int n_in,
                              void* d_out, int out_size, void* d_ws, size_t ws_size,
                              hipStream_t stream) {
  const float* X     = (const float*)d_in[0];  // [4,2048,768] f32
  const float* Wqkv  = (const float*)d_in[1];  // [2304,768]   f32
  const float* Wproj = (const float*)d_in[2];  // [768,768]    f32
  float* out = (float*)d_out;                  // [4,2048,768] f32

  const size_t SZ_QK = (size_t)8192 * 1536 * 2;       // 25.2 MB
  const size_t SZ_VT = (size_t)3072 * 2048 * 2;       // 12.6 MB
  const size_t SZ_SC = (size_t)12 * 136 * 16384 * 2;  // 53.5 MB
  const size_t SZ_AO = (size_t)8192 * 768 * 2;        // 12.6 MB
  const size_t SZ_WQ = (size_t)2304 * 768 * 2;        //  3.5 MB

  char* ws = (char*)d_ws;
  unsigned short* QKb = (unsigned short*)ws;
  unsigned short* VTb = (unsigned short*)(ws + SZ_QK);
  unsigned short* Scb = (unsigned short*)(ws + SZ_QK + SZ_VT);
  unsigned short* Xb  = Scb;  // alias: Xb dead before Sc written
  unsigned short* AOb = (unsigned short*)(ws + SZ_QK + SZ_VT + SZ_SC);
  unsigned short* Wqb = (unsigned short*)(ws + SZ_QK + SZ_VT + SZ_SC + SZ_AO);
  unsigned short* Wpb = (unsigned short*)(ws + SZ_QK + SZ_VT + SZ_SC + SZ_AO + SZ_WQ);

  dim3 blk(256, 1, 1);
  // 0) one-time f32 -> f16 conversions
  cvt_kernel<<<dim3(3072, 1, 1), blk, 0, stream>>>(X, Xb, 786432);
  cvt_kernel<<<dim3(864, 1, 1), blk, 0, stream>>>(Wqkv, Wqb, 221184);
  cvt_kernel<<<dim3(288, 1, 1), blk, 0, stream>>>(Wproj, Wpb, 73728);
  // 1) QKV projection (V stored transposed)
  gemm_async_kernel<1, false><<<dim3(18, 64, 1), blk, 0, stream>>>(
      Xb, Wqb, QKb, VTb, 768, 1536);
  // 2) dense causal attention as GEMMs
  gemm_sc_kernel<<<dim3(136, 12, 1), blk, 0, stream>>>(QKb, Scb);
  softmax_kernel<<<dim3(16, 12, 1), blk, 0, stream>>>(Scb);
  gemm_pv_kernel<<<dim3(32, 12, 1), blk, 0, stream>>>(Scb, VTb, AOb);
  // 3) output projection, f32 store
  gemm_async_kernel<0, true><<<dim3(6, 64, 1), blk, 0, stream>>>(
      AOb, Wpb, out, (unsigned short*)nullptr, 768, 768);
}

// Round 11
// 260.403 us; speedup vs baseline: 1.4691x; 1.4515x over previous
//
#include <hip/hip_runtime.h>

using v8h = __attribute__((ext_vector_type(8))) _Float16;       // 8 f16 MFMA frag
using v4f = __attribute__((ext_vector_type(4))) float;          // MFMA acc
using v4u = __attribute__((ext_vector_type(4))) unsigned short; // 8B packed
using v8u = __attribute__((ext_vector_type(8))) unsigned short; // 16B copy

// fp32 <-> fp16
__device__ __forceinline__ unsigned short f2h(float x) {
  _Float16 h = (_Float16)x;
  return __builtin_bit_cast(unsigned short, h);
}
__device__ __forceinline__ float h2f(unsigned short u) {
  return (float)__builtin_bit_cast(_Float16, u);
}

// async global -> LDS, 16 bytes per lane (global_load_lds_dwordx4)
__device__ __forceinline__ void gl_lds16(const unsigned short* g, unsigned short* l) {
  __builtin_amdgcn_global_load_lds(
      (const __attribute__((address_space(1))) unsigned int*)g,
      (__attribute__((address_space(3))) unsigned int*)l, 16, 0, 0);
}

// ---------------------------------------------------------------------------
// f32 -> f16 bulk convert, 8 elems/thread
// ---------------------------------------------------------------------------
__global__ void cvt_kernel(const float* __restrict__ src,
                           unsigned short* __restrict__ dst, int n8) {
  int i = blockIdx.x * 256 + threadIdx.x;
  if (i >= n8) return;
  const float* p = src + (size_t)i * 8;
  float4 a = *(const float4*)p;
  float4 b = *(const float4*)(p + 4);
  v8u o = {f2h(a.x), f2h(a.y), f2h(a.z), f2h(a.w),
           f2h(b.x), f2h(b.y), f2h(b.z), f2h(b.w)};
  *(v8u*)(dst + (size_t)i * 8) = o;
}

// ---------------------------------------------------------------------------
// f16 GEMM, m97 recipe: C[m,n] = sum_k A[m,k]*Bw[n,k], 128x128 tile, BK=32.
// MODE 1 (QKV): cols<1536 -> C f16 (ldc=1536); cols>=1536 -> VT transposed f16.
// MODE 0: plain store (f32 if OF else f16).
// ---------------------------------------------------------------------------
template <int MODE, bool OF>
__global__ __launch_bounds__(256, 2)
void gemm_async_kernel(const unsigned short* __restrict__ A,
                       const unsigned short* __restrict__ Bw,
                       void* __restrict__ Cv, unsigned short* __restrict__ VT,
                       int K, int ldc) {
  __shared__ unsigned short As[4096];
  __shared__ unsigned short Bs[4096];

  const int t    = threadIdx.x;
  const int ln   = t & 63;
  const int wv   = t >> 6;
  const int quad = ln >> 4;
  const int L    = ln & 15;
  const int wm   = (wv >> 1) * 64;
  const int wn   = (wv & 1) * 64;
  const long m0  = (long)blockIdx.y * 128;
  const long n0  = (long)blockIdx.x * 128;

  v4f acc[4][4];
#pragma unroll
  for (int i = 0; i < 4; i++)
#pragma unroll
    for (int j = 0; j < 4; j++) acc[i][j] = (v4f){0.f, 0.f, 0.f, 0.f};

  const int ar = t >> 2;
  const int ac = (t & 3) * 8;
  const unsigned short* Ag = A + (m0 + ar) * (long)K + ac;
  const unsigned short* Bg = Bw + (n0 + ar) * (long)K + ac;
  unsigned short* la = &As[t * 8];
  unsigned short* lb = &Bs[t * 8];
  const long rowskip = 64L * K;

  for (int k0 = 0; k0 < K; k0 += 32) {
    gl_lds16(Ag + k0, la);
    gl_lds16(Ag + rowskip + k0, la + 2048);
    gl_lds16(Bg + k0, lb);
    gl_lds16(Bg + rowskip + k0, lb + 2048);
    __syncthreads();

    v8h af[4], bfr[4];
#pragma unroll
    for (int i = 0; i < 4; i++)
      af[i] = *(const v8h*)(&As[(wm + i * 16 + L) * 32 + quad * 8]);
#pragma unroll
    for (int j = 0; j < 4; j++)
      bfr[j] = *(const v8h*)(&Bs[(wn + j * 16 + L) * 32 + quad * 8]);
#pragma unroll
    for (int i = 0; i < 4; i++)
#pragma unroll
      for (int j = 0; j < 4; j++)
        acc[i][j] = __builtin_amdgcn_mfma_f32_16x16x32_f16(af[i], bfr[j], acc[i][j], 0, 0, 0);
    __syncthreads();
  }

  if (MODE == 0 || n0 < 1536) {
#pragma unroll
    for (int i = 0; i < 4; i++)
#pragma unroll
      for (int j = 0; j < 4; j++)
#pragma unroll
        for (int r = 0; r < 4; r++) {
          long row = m0 + wm + i * 16 + quad * 4 + r;
          long col = n0 + wn + j * 16 + L;
          if (OF) ((float*)Cv)[row * ldc + col] = acc[i][j][r];
          else    ((unsigned short*)Cv)[row * ldc + col] = f2h(acc[i][j][r]);
        }
  } else {
#pragma unroll
    for (int i = 0; i < 4; i++)
#pragma unroll
      for (int j = 0; j < 4; j++) {
        int colp   = (int)(n0 + wn + j * 16 + L) - 1536;
        int h      = colp >> 8;
        int d      = colp & 255;
        long token = m0 + wm + i * 16 + quad * 4;
        int b  = (int)(token >> 11);
        int tk = (int)(token & 2047);
        v4u val = {f2h(acc[i][j][0]), f2h(acc[i][j][1]), f2h(acc[i][j][2]), f2h(acc[i][j][3])};
        *(v4u*)(&VT[((long)(b * 3 + h) * 256 + d) * 2048 + tk]) = val;
      }
  }
}

// ---------------------------------------------------------------------------
// Score GEMM: S_tile(i,j)[128][128] = Q_block_i . K_block_j^T (raw, unscaled).
// Packed lower-tri storage: slot = bh*136 + i(i+1)/2 + j. Grid (136, 12).
// ---------------------------------------------------------------------------
__global__ __launch_bounds__(256, 2)
void gemm_sc_kernel(const unsigned short* __restrict__ QK,
                    unsigned short* __restrict__ Sc) {
  __shared__ unsigned short As[4096];
  __shared__ unsigned short Bs[4096];

  const int t    = threadIdx.x;
  const int ln   = t & 63;
  const int wv   = t >> 6;
  const int quad = ln >> 4;
  const int L    = ln & 15;
  const int wm   = (wv >> 1) * 64;
  const int wn   = (wv & 1) * 64;

  int x = (int)blockIdx.x, i = 0;
  while (x >= i + 1) { x -= i + 1; i++; }
  const int j  = x;
  const int bh = (int)blockIdx.y;
  const int b  = bh / 3, h = bh % 3;
  const long tokA = (long)b * 2048 + i * 128;
  const long tokB = (long)b * 2048 + j * 128;

  v4f acc[4][4];
#pragma unroll
  for (int ii = 0; ii < 4; ii++)
#pragma unroll
    for (int jj = 0; jj < 4; jj++) acc[ii][jj] = (v4f){0.f, 0.f, 0.f, 0.f};

  const int ar = t >> 2;
  const int ac = (t & 3) * 8;
  const unsigned short* Ag = QK + (tokA + ar) * 1536 + h * 256 + ac;
  const unsigned short* Bg = QK + (tokB + ar) * 1536 + 768 + h * 256 + ac;
  unsigned short* la = &As[t * 8];
  unsigned short* lb = &Bs[t * 8];
  const long rowskip = 64L * 1536;

  for (int k0 = 0; k0 < 256; k0 += 32) {
    gl_lds16(Ag + k0, la);
    gl_lds16(Ag + rowskip + k0, la + 2048);
    gl_lds16(Bg + k0, lb);
    gl_lds16(Bg + rowskip + k0, lb + 2048);
    __syncthreads();

    v8h af[4], bfr[4];
#pragma unroll
    for (int ii = 0; ii < 4; ii++)
      af[ii] = *(const v8h*)(&As[(wm + ii * 16 + L) * 32 + quad * 8]);
#pragma unroll
    for (int jj = 0; jj < 4; jj++)
      bfr[jj] = *(const v8h*)(&Bs[(wn + jj * 16 + L) * 32 + quad * 8]);
#pragma unroll
    for (int ii = 0; ii < 4; ii++)
#pragma unroll
      for (int jj = 0; jj < 4; jj++)
        acc[ii][jj] = __builtin_amdgcn_mfma_f32_16x16x32_f16(af[ii], bfr[jj], acc[ii][jj], 0, 0, 0);
    __syncthreads();
  }

  unsigned short* Sb = Sc + ((long)bh * 136 + blockIdx.x) * 16384;
#pragma unroll
  for (int ii = 0; ii < 4; ii++)
#pragma unroll
    for (int jj = 0; jj < 4; jj++)
#pragma unroll
      for (int r = 0; r < 4; r++) {
        int row = wm + ii * 16 + quad * 4 + r;
        int col = wn + jj * 16 + L;
        Sb[row * 128 + col] = f2h(acc[ii][jj][r]);
      }
}

// ---------------------------------------------------------------------------
// Softmax, one WAVE per q-row; whole row cached in registers (<=32 f32/lane).
// Single global read + single write. Block = 4 waves; grid (512, 12).
// Heavy rows (large i) dispatched first. Masked cols written as exact 0.
// ---------------------------------------------------------------------------
__global__ __launch_bounds__(256, 4)
void softmax_kernel(unsigned short* __restrict__ Sc) {
  const int tt   = threadIdx.x;
  const int wv   = tt >> 6;
  const int lane = tt & 63;
  const int bh   = (int)blockIdx.y;

  const int r = 2047 - ((int)blockIdx.x * 4 + wv);  // heavy rows first
  const int i = r >> 7;
  const int rowloc = r & 127;
  const long base = ((long)bh * 136 + (long)i * (i + 1) / 2) * 16384 + rowloc * 128;
  const int Lrow = (i + 1) * 128;
  const int nch = (i + 4) >> 2;  // ceil((i+1)/4) chunks of 512 cols

  float xs[4][8];
  float mx = -1e30f;
  for (int k = 0; k < nch; k++) {
    int c0 = k * 512 + lane * 8;
    if (c0 < Lrow) {
      int j = c0 >> 7;
      v8u v = *(const v8u*)(Sc + base + (long)j * 16384 + (c0 & 127));
#pragma unroll
      for (int e = 0; e < 8; e++) {
        float f = (c0 + e <= r) ? h2f(v[e]) * 0.0625f : -1e30f;
        xs[k][e] = f;
        mx = fmaxf(mx, f);
      }
    } else {
#pragma unroll
      for (int e = 0; e < 8; e++) xs[k][e] = -1e30f;
    }
  }
#pragma unroll
  for (int d = 1; d < 64; d <<= 1) mx = fmaxf(mx, __shfl_xor(mx, d));

  float sum = 0.f;
  for (int k = 0; k < nch; k++)
#pragma unroll
    for (int e = 0; e < 8; e++) {
      float ex = __expf(xs[k][e] - mx);  // masked: exp(-huge) = 0
      xs[k][e] = ex;
      sum += ex;
    }
#pragma unroll
  for (int d = 1; d < 64; d <<= 1) sum += __shfl_xor(sum, d);
  const float inv = 1.0f / sum;

  for (int k = 0; k < nch; k++) {
    int c0 = k * 512 + lane * 8;
    if (c0 < Lrow) {
      int j = c0 >> 7;
      v8u o;
#pragma unroll
      for (int e = 0; e < 8; e++) o[e] = f2h(xs[k][e] * inv);
      *(v8u*)(Sc + base + (long)j * 16384 + (c0 & 127)) = o;
    }
  }
}

// ---------------------------------------------------------------------------
// PV GEMM, j-parity split: partial(i,nh,par) = sum_{j==par (mod 2), j<=i}
// P(i,j).V_j, written f16 to Pp. Grid x: 64 = (16 i heavy-first)x(2 nh)x(2 par).
// ---------------------------------------------------------------------------
__global__ __launch_bounds__(256, 2)
void gemm_pv_kernel(const unsigned short* __restrict__ Sc,
                    const unsigned short* __restrict__ VT,
                    unsigned short* __restrict__ Pp) {
  __shared__ unsigned short As[4096];
  __shared__ unsigned short Bs[4096];

  const int t    = threadIdx.x;
  const int ln   = t & 63;
  const int wv   = t >> 6;
  const int quad = ln >> 4;
  const int L    = ln & 15;
  const int wm   = (wv >> 1) * 64;
  const int wn   = (wv & 1) * 64;

  const int ix  = (int)blockIdx.x;
  const int i   = 15 - (ix >> 2);  // heavy first
  const int nh  = (ix >> 1) & 1;
  const int par = ix & 1;
  const int bh  = (int)blockIdx.y;

  v4f acc[4][4];
#pragma unroll
  for (int ii = 0; ii < 4; ii++)
#pragma unroll
    for (int jj = 0; jj < 4; jj++) acc[ii][jj] = (v4f){0.f, 0.f, 0.f, 0.f};

  const int ar = t >> 2;
  const int ac = (t & 3) * 8;
  const unsigned short* Abase =
      Sc + ((long)bh * 136 + (long)i * (i + 1) / 2) * 16384 + ar * 128 + ac;
  const unsigned short* Bg =
      VT + ((long)bh * 256 + nh * 128 + ar) * 2048 + ac;
  unsigned short* la = &As[t * 8];
  unsigned short* lb = &Bs[t * 8];

  for (int j = par; j <= i; j += 2) {
    const unsigned short* Aj = Abase + (long)j * 16384;
    const unsigned short* Bj = Bg + j * 128;
#pragma unroll
    for (int k0 = 0; k0 < 128; k0 += 32) {
      gl_lds16(Aj + k0, la);
      gl_lds16(Aj + 64 * 128 + k0, la + 2048);
      gl_lds16(Bj + k0, lb);
      gl_lds16(Bj + 64 * 2048 + k0, lb + 2048);
      __syncthreads();

      v8h af[4], bfr[4];
#pragma unroll
      for (int ii = 0; ii < 4; ii++)
        af[ii] = *(const v8h*)(&As[(wm + ii * 16 + L) * 32 + quad * 8]);
#pragma unroll
      for (int jj = 0; jj < 4; jj++)
        bfr[jj] = *(const v8h*)(&Bs[(wn + jj * 16 + L) * 32 + quad * 8]);
#pragma unroll
      for (int ii = 0; ii < 4; ii++)
#pragma unroll
        for (int jj = 0; jj < 4; jj++)
          acc[ii][jj] = __builtin_amdgcn_mfma_f32_16x16x32_f16(af[ii], bfr[jj], acc[ii][jj], 0, 0, 0);
      __syncthreads();
    }
  }

  unsigned short* Pb = Pp + ((((long)bh * 16 + i) * 2 + nh) * 2 + par) * 16384;
#pragma unroll
  for (int ii = 0; ii < 4; ii++)
#pragma unroll
    for (int jj = 0; jj < 4; jj++)
#pragma unroll
      for (int r = 0; r < 4; r++) {
        int row = wm + ii * 16 + quad * 4 + r;
        int col = wn + jj * 16 + L;
        Pb[row * 128 + col] = f2h(acc[ii][jj][r]);
      }
}

// ---------------------------------------------------------------------------
// Combine the two parity partials -> AO. Grid (32 = 16i x 2nh, 12).
// Thread: row = tid>>1, 64-col half (tid&1). 8 x v8u.
// ---------------------------------------------------------------------------
__global__ __launch_bounds__(256, 4)
void pv_combine_kernel(const unsigned short* __restrict__ Pp,
                       unsigned short* __restrict__ AO) {
  const int i  = (int)blockIdx.x >> 1;
  const int nh = (int)blockIdx.x & 1;
  const int bh = (int)blockIdx.y;
  const int b  = bh / 3, h = bh % 3;

  const int tid = threadIdx.x;
  const int row = tid >> 1;
  const int cs  = (tid & 1) * 64;

  const unsigned short* P0 = Pp + ((((long)bh * 16 + i) * 2 + nh) * 2 + 0) * 16384 + row * 128 + cs;
  const unsigned short* P1 = P0 + 16384;
  unsigned short* Or = AO + ((long)b * 2048 + i * 128 + row) * 768 + h * 256 + nh * 128 + cs;
#pragma unroll
  for (int q = 0; q < 8; q++) {
    v8u a = *(const v8u*)(P0 + q * 8);
    v8u c = *(const v8u*)(P1 + q * 8);
    v8u o;
#pragma unroll
    for (int e = 0; e < 8; e++) o[e] = f2h(h2f(a[e]) + h2f(c[e]));
    *(v8u*)(Or + q * 8) = o;
  }
}

// ---------------------------------------------------------------------------
extern "C" void kernel_launch(void* const* d_in, const int* in_sizes, int n_in,
                              void* d_out, int out_size, void* d_ws, size_t ws_size,
                              hipStream_t stream) {
  const float* X     = (const float*)d_in[0];  // [4,2048,768] f32
  const float* Wqkv  = (const float*)d_in[1];  // [2304,768]   f32
  const float* Wproj = (const float*)d_in[2];  // [768,768]    f32
  float* out = (float*)d_out;                  // [4,2048,768] f32

  const size_t SZ_QK = (size_t)8192 * 1536 * 2;       // 25.2 MB
  const size_t SZ_VT = (size_t)3072 * 2048 * 2;       // 12.6 MB
  const size_t SZ_SC = (size_t)12 * 136 * 16384 * 2;  // 53.5 MB
  const size_t SZ_AO = (size_t)8192 * 768 * 2;        // 12.6 MB
  const size_t SZ_WQ = (size_t)2304 * 768 * 2;        //  3.5 MB

  char* ws = (char*)d_ws;
  unsigned short* QKb = (unsigned short*)ws;
  unsigned short* Ppb = QKb;  // alias: QK dead after gemm_sc; Pp = 12*16*2*2*16384*2 B == SZ_QK
  unsigned short* VTb = (unsigned short*)(ws + SZ_QK);
  unsigned short* Scb = (unsigned short*)(ws + SZ_QK + SZ_VT);
  unsigned short* Xb  = Scb;  // alias: Xb dead before Sc written
  unsigned short* AOb = (unsigned short*)(ws + SZ_QK + SZ_VT + SZ_SC);
  unsigned short* Wqb = (unsigned short*)(ws + SZ_QK + SZ_VT + SZ_SC + SZ_AO);
  unsigned short* Wpb = (unsigned short*)(ws + SZ_QK + SZ_VT + SZ_SC + SZ_AO + SZ_WQ);

  dim3 blk(256, 1, 1);
  // 0) one-time f32 -> f16 conversions
  cvt_kernel<<<dim3(3072, 1, 1), blk, 0, stream>>>(X, Xb, 786432);
  cvt_kernel<<<dim3(864, 1, 1), blk, 0, stream>>>(Wqkv, Wqb, 221184);
  cvt_kernel<<<dim3(288, 1, 1), blk, 0, stream>>>(Wproj, Wpb, 73728);
  // 1) QKV projection (V stored transposed)
  gemm_async_kernel<1, false><<<dim3(18, 64, 1), blk, 0, stream>>>(
      Xb, Wqb, QKb, VTb, 768, 1536);
  // 2) dense causal attention as GEMMs
  gemm_sc_kernel<<<dim3(136, 12, 1), blk, 0, stream>>>(QKb, Scb);
  softmax_kernel<<<dim3(512, 12, 1), blk, 0, stream>>>(Scb);
  gemm_pv_kernel<<<dim3(64, 12, 1), blk, 0, stream>>>(Scb, VTb, Ppb);
  pv_combine_kernel<<<dim3(32, 12, 1), blk, 0, stream>>>(Ppb, AOb);
  // 3) output projection, f32 store
  gemm_async_kernel<0, true><<<dim3(6, 64, 1), blk, 0, stream>>>(
      AOb, Wpb, out, (unsigned short*)nullptr, 768, 768);
}